// Round 10
// baseline (118.628 us; speedup 1.0000x reference)
//
#include <hip/hip_runtime.h>

#define NN 50000
#define TT 12
#define QQ 3
#define HH 64
#define KK 32
#define TQ 36   // T*Q
#define NLEV 4

// bf16 <-> fp32 helpers (RNE pack). State is stored bf16 to halve gather line
// traffic (72B rows: 2 cache lines vs fp32's 144B = always 3 lines) and to fit
// the 3.6MB gather source in a 4MiB per-XCD L2. Accumulation stays fp32.
__device__ __forceinline__ float bf2f(unsigned short u) {
    union { unsigned int i; float f; } c; c.i = ((unsigned int)u) << 16; return c.f;
}
__device__ __forceinline__ unsigned short f2bf(float f) {
    union { float f; unsigned int i; } c; c.f = f;
    unsigned int u = c.i;
    u += 0x7FFFu + ((u >> 16) & 1u);
    return (unsigned short)(u >> 16);
}

// ---------------------------------------------------------------------------
// Projection in XW-space (bf16 out): xw[node][t][q] = proj[node,t,q]*sc[node,t].
// Level update in XW-space is a pure gather-sum (scaler cancels).
// ---------------------------------------------------------------------------
__global__ __launch_bounds__(256) void proj_xw_kernel(
    const float* __restrict__ gnn, const float* __restrict__ w,
    const float* __restrict__ b, const float* __restrict__ scaler,
    unsigned short* __restrict__ xw, int nrows)
{
    const int lane = threadIdx.x & 63;
    const int sub  = lane & 15;
    const int h0   = sub * 4;

    float wreg[4][3];
#pragma unroll
    for (int j = 0; j < 4; ++j)
#pragma unroll
        for (int q = 0; q < 3; ++q)
            wreg[j][q] = w[(h0 + j) * 3 + q];
    const float b0 = b[0], b1 = b[1], b2 = b[2];

    const int gwave  = (blockIdx.x * blockDim.x + threadIdx.x) >> 6;
    const int nwaves = (gridDim.x * blockDim.x) >> 6;
    const int nquads = nrows >> 2;

    for (int quad = gwave; quad < nquads; quad += nwaves) {
        const float4 g = *reinterpret_cast<const float4*>(gnn + (size_t)quad * 256 + lane * 4);
        float a0 = g.x * wreg[0][0] + g.y * wreg[1][0] + g.z * wreg[2][0] + g.w * wreg[3][0];
        float a1 = g.x * wreg[0][1] + g.y * wreg[1][1] + g.z * wreg[2][1] + g.w * wreg[3][1];
        float a2 = g.x * wreg[0][2] + g.y * wreg[1][2] + g.z * wreg[2][2] + g.w * wreg[3][2];
#pragma unroll
        for (int off = 8; off > 0; off >>= 1) {
            a0 += __shfl_down(a0, off);
            a1 += __shfl_down(a1, off);
            a2 += __shfl_down(a2, off);
        }
        if (sub == 0) {
            const int row = quad * 4 + (lane >> 4);   // row = node*T + t
            const float s = scaler[row];
            xw[row * 3 + 0] = f2bf((a0 + b0) * s);
            xw[row * 3 + 1] = f2bf((a1 + b1) * s);
            xw[row * 3 + 2] = f2bf((a2 + b2) * s);
        }
    }
}

// ---------------------------------------------------------------------------
// Gather-sum core, bf16 source, max MLP: all 32 keys preloaded (8x int4),
// all 32 gathers issued before any use (R9's win), 4 parallel fp32 accs.
// ---------------------------------------------------------------------------
__device__ __forceinline__ float gather_sum(
    const unsigned short* __restrict__ cur, const int* __restrict__ keybom,
    int node, int tq)
{
    const int4* kb4 = reinterpret_cast<const int4*>(keybom + (size_t)node * KK);
    int keys[KK];
#pragma unroll
    for (int kk = 0; kk < KK / 4; ++kk) {
        const int4 k4 = kb4[kk];
        keys[kk * 4 + 0] = k4.x;
        keys[kk * 4 + 1] = k4.y;
        keys[kk * 4 + 2] = k4.z;
        keys[kk * 4 + 3] = k4.w;
    }
    float v[KK];
#pragma unroll
    for (int k = 0; k < KK; ++k) {
        const int key = keys[k];
        v[k] = (key >= 0) ? bf2f(cur[(size_t)key * TQ + tq]) : 0.0f;
    }
    float s0 = 0.f, s1 = 0.f, s2 = 0.f, s3 = 0.f;
#pragma unroll
    for (int k = 0; k < KK; k += 4) {
        s0 += v[k + 0];
        s1 += v[k + 1];
        s2 += v[k + 2];
        s3 += v[k + 3];
    }
    return (s0 + s1) + (s2 + s3);
}

// ---------------------------------------------------------------------------
// One level in XW-space, ping-pong (bf16 state).
// ---------------------------------------------------------------------------
__global__ __launch_bounds__(256) void level_kernel(
    const unsigned short* __restrict__ cur, const int* __restrict__ keybom,
    const int* __restrict__ lvl, unsigned short* __restrict__ nxt, int level)
{
    const int idx  = blockIdx.x * blockDim.x + threadIdx.x;
    if (idx >= NN * TQ) return;
    const int node = idx / TQ;
    const int tq   = idx - node * TQ;

    if (lvl[node] != level) {
        nxt[idx] = cur[idx];
        return;
    }
    nxt[idx] = f2bf(gather_sum(cur, keybom, node, tq));
}

// ---------------------------------------------------------------------------
// Final level fused with XW -> out conversion (divide by scaler, fp32 out).
// ---------------------------------------------------------------------------
__global__ __launch_bounds__(256) void level_final_kernel(
    const unsigned short* __restrict__ cur, const float* __restrict__ scaler,
    const int* __restrict__ keybom, const int* __restrict__ lvl,
    float* __restrict__ out, int level)
{
    const int idx  = blockIdx.x * blockDim.x + threadIdx.x;
    if (idx >= NN * TQ) return;
    const int node = idx / TQ;

    float v;
    if (lvl[node] != level) {
        v = bf2f(cur[idx]);
    } else {
        const int tq = idx - node * TQ;
        v = gather_sum(cur, keybom, node, tq);
    }
    out[idx] = v / scaler[idx / 3];      // idx/3 == node*T + t
}

extern "C" void kernel_launch(void* const* d_in, const int* in_sizes, int n_in,
                              void* d_out, int out_size, void* d_ws, size_t ws_size,
                              hipStream_t stream)
{
    const float* gnn    = (const float*)d_in[0];
    const float* w      = (const float*)d_in[1];
    const float* b      = (const float*)d_in[2];
    const float* scaler = (const float*)d_in[3];
    const int*   keybom = (const int*)d_in[4];
    const int*   lvl    = (const int*)d_in[5];
    float* out = (float*)d_out;

    char* ws = (char*)d_ws;
    unsigned short* bufA = (unsigned short*)ws;                        // 3.6 MB
    unsigned short* bufB = (unsigned short*)(ws + (size_t)NN * TQ * 2);// 3.6 MB

    proj_xw_kernel<<<2048, 256, 0, stream>>>(gnn, w, b, scaler, bufA, NN * TT);

    const int blocks = (NN * TQ + 255) / 256;
    level_kernel<<<blocks, 256, 0, stream>>>(bufA, keybom, lvl, bufB, 1);
    level_kernel<<<blocks, 256, 0, stream>>>(bufB, keybom, lvl, bufA, 2);
    level_final_kernel<<<blocks, 256, 0, stream>>>(bufA, scaler, keybom, lvl, out, 3);
}

// Round 11
// 63.611 us; speedup vs baseline: 1.8649x; 1.8649x over previous
//
#include <hip/hip_runtime.h>

#define NN 50000
#define TT 12
#define QQ 3
#define HH 64
#define KK 32
#define TQ 36    // T*Q
#define PR 18    // TQ/2 packed bf16 pairs per row
#define NLEV 4

// State is XW = out*scaler in bf16, packed 2-per-dword. Level recursion in
// XW-space is a pure gather-sum (scaler cancels; R8 identity). bf16 rows are
// 72B = 2 cache lines (fp32 was 3). R10 regressed because ushort gathers +
// per-element converts serialized the loads; here gathers are DWORD loads
// (R9's proven-fast pattern) and conversion happens after, on registers.
__device__ __forceinline__ float bf2f(unsigned int u16) {
    union { unsigned int i; float f; } c; c.i = u16 << 16; return c.f;
}
__device__ __forceinline__ unsigned short f2bf(float f) {
    union { float f; unsigned int i; } c; c.f = f;
    unsigned int u = c.i;
    u += 0x7FFFu + ((u >> 16) & 1u);
    return (unsigned short)(u >> 16);
}

// ---------------------------------------------------------------------------
// Projection in XW-space (bf16 out): xw[row*3+q] = (proj+b)[row,q] * sc[row].
// ---------------------------------------------------------------------------
__global__ __launch_bounds__(256) void proj_xw_kernel(
    const float* __restrict__ gnn, const float* __restrict__ w,
    const float* __restrict__ b, const float* __restrict__ scaler,
    unsigned short* __restrict__ xw, int nrows)
{
    const int lane = threadIdx.x & 63;
    const int sub  = lane & 15;
    const int h0   = sub * 4;

    float wreg[4][3];
#pragma unroll
    for (int j = 0; j < 4; ++j)
#pragma unroll
        for (int q = 0; q < 3; ++q)
            wreg[j][q] = w[(h0 + j) * 3 + q];
    const float b0 = b[0], b1 = b[1], b2 = b[2];

    const int gwave  = (blockIdx.x * blockDim.x + threadIdx.x) >> 6;
    const int nwaves = (gridDim.x * blockDim.x) >> 6;
    const int nquads = nrows >> 2;

    for (int quad = gwave; quad < nquads; quad += nwaves) {
        const float4 g = *reinterpret_cast<const float4*>(gnn + (size_t)quad * 256 + lane * 4);
        float a0 = g.x * wreg[0][0] + g.y * wreg[1][0] + g.z * wreg[2][0] + g.w * wreg[3][0];
        float a1 = g.x * wreg[0][1] + g.y * wreg[1][1] + g.z * wreg[2][1] + g.w * wreg[3][1];
        float a2 = g.x * wreg[0][2] + g.y * wreg[1][2] + g.z * wreg[2][2] + g.w * wreg[3][2];
#pragma unroll
        for (int off = 8; off > 0; off >>= 1) {
            a0 += __shfl_down(a0, off);
            a1 += __shfl_down(a1, off);
            a2 += __shfl_down(a2, off);
        }
        if (sub == 0) {
            const int row = quad * 4 + (lane >> 4);   // row = node*T + t
            const float s = scaler[row];
            xw[row * 3 + 0] = f2bf((a0 + b0) * s);
            xw[row * 3 + 1] = f2bf((a1 + b1) * s);
            xw[row * 3 + 2] = f2bf((a2 + b2) * s);
        }
    }
}

// ---------------------------------------------------------------------------
// Gather-sum for one bf16 pair: 32 DWORD gathers all issued before any use
// (preloaded keys via 8x int4), then convert+accumulate on registers.
// ---------------------------------------------------------------------------
__device__ __forceinline__ float2 gather_sum_pair(
    const unsigned int* __restrict__ cur32, const int* __restrict__ keybom,
    int node, int p)
{
    const int4* kb4 = reinterpret_cast<const int4*>(keybom + (size_t)node * KK);
    int keys[KK];
#pragma unroll
    for (int kk = 0; kk < KK / 4; ++kk) {
        const int4 k4 = kb4[kk];
        keys[kk * 4 + 0] = k4.x;
        keys[kk * 4 + 1] = k4.y;
        keys[kk * 4 + 2] = k4.z;
        keys[kk * 4 + 3] = k4.w;
    }
    unsigned int u[KK];
#pragma unroll
    for (int k = 0; k < KK; ++k) {
        const int key = keys[k];
        u[k] = (key >= 0) ? cur32[(size_t)key * PR + p] : 0u;  // 32 dwords in flight
    }
    float l0 = 0.f, l1 = 0.f, h0 = 0.f, h1 = 0.f;
#pragma unroll
    for (int k = 0; k < KK; k += 2) {
        l0 += bf2f(u[k] & 0xFFFFu);
        h0 += bf2f(u[k] >> 16);
        l1 += bf2f(u[k + 1] & 0xFFFFu);
        h1 += bf2f(u[k + 1] >> 16);
    }
    return make_float2(l0 + l1, h0 + h1);
}

// ---------------------------------------------------------------------------
// One level in XW-space, ping-pong. Thread = (node, pair p).
// ---------------------------------------------------------------------------
__global__ __launch_bounds__(256) void level_kernel(
    const unsigned int* __restrict__ cur32, const int* __restrict__ keybom,
    const int* __restrict__ lvl, unsigned int* __restrict__ nxt32, int level)
{
    const int idx  = blockIdx.x * blockDim.x + threadIdx.x;
    if (idx >= NN * PR) return;
    const int node = idx / PR;
    const int p    = idx - node * PR;

    if (lvl[node] != level) {                 // pass-through: dword copy
        nxt32[idx] = cur32[idx];
        return;
    }
    const float2 s = gather_sum_pair(cur32, keybom, node, p);
    nxt32[idx] = (unsigned int)f2bf(s.x) | ((unsigned int)f2bf(s.y) << 16);
}

// ---------------------------------------------------------------------------
// Final level fused with XW -> out conversion: out = XW / scaler, fp32,
// float2 store (elements 2p, 2p+1 of the node's row).
// ---------------------------------------------------------------------------
__global__ __launch_bounds__(256) void level_final_kernel(
    const unsigned int* __restrict__ cur32, const float* __restrict__ scaler,
    const int* __restrict__ keybom, const int* __restrict__ lvl,
    float* __restrict__ out, int level)
{
    const int idx  = blockIdx.x * blockDim.x + threadIdx.x;
    if (idx >= NN * PR) return;
    const int node = idx / PR;
    const int p    = idx - node * PR;

    float v0, v1;
    if (lvl[node] != level) {
        const unsigned int u = cur32[idx];
        v0 = bf2f(u & 0xFFFFu);
        v1 = bf2f(u >> 16);
    } else {
        const float2 s = gather_sum_pair(cur32, keybom, node, p);
        v0 = s.x;
        v1 = s.y;
    }
    const int e0 = node * TQ + 2 * p;               // global element index
    const float2 r = make_float2(v0 / scaler[e0 / 3],
                                 v1 / scaler[(e0 + 1) / 3]);
    *reinterpret_cast<float2*>(out + e0) = r;       // 8B-aligned (144n + 8p)
}

extern "C" void kernel_launch(void* const* d_in, const int* in_sizes, int n_in,
                              void* d_out, int out_size, void* d_ws, size_t ws_size,
                              hipStream_t stream)
{
    const float* gnn    = (const float*)d_in[0];
    const float* w      = (const float*)d_in[1];
    const float* b      = (const float*)d_in[2];
    const float* scaler = (const float*)d_in[3];
    const int*   keybom = (const int*)d_in[4];
    const int*   lvl    = (const int*)d_in[5];
    float* out = (float*)d_out;

    char* ws = (char*)d_ws;
    unsigned short* bufA = (unsigned short*)ws;                         // 3.6 MB
    unsigned short* bufB = (unsigned short*)(ws + (size_t)NN * TQ * 2); // 3.6 MB

    proj_xw_kernel<<<2048, 256, 0, stream>>>(gnn, w, b, scaler, bufA, NN * TT);

    const int blocks = (NN * PR + 255) / 256;
    level_kernel<<<blocks, 256, 0, stream>>>((const unsigned int*)bufA, keybom, lvl,
                                             (unsigned int*)bufB, 1);
    level_kernel<<<blocks, 256, 0, stream>>>((const unsigned int*)bufB, keybom, lvl,
                                             (unsigned int*)bufA, 2);
    level_final_kernel<<<blocks, 256, 0, stream>>>((const unsigned int*)bufA, scaler,
                                                   keybom, lvl, out, 3);
}